// Round 6
// baseline (144.706 us; speedup 1.0000x reference)
//
#include <hip/hip_runtime.h>

// LocalAttention, MFMA bf16, round 13 = r11 structure + entry-hoisted K loads.
// B=4, L=2048, H=16, E=D=64, window=64. fp32 in/out; bf16 MFMA; fp32 accumulate.
//
// r12 post-mortem: gload_lds K + 1 barrier left dur at 40.4us, HBM 2.9 TB/s.
// Same trace: fillBufferAligned = 6.6 TB/s at 8.4% occupancy, 8 VGPRs.
// Occupancy was NEVER the limiter. Duty-cycle model closes the arithmetic:
// memory pipe active only in the ~2k-cy load window, idle for the ~10k-cy
// barrier-serialized compute phase; 3 resident blocks -> ~50% duty = measured
// 46% of achievable. Lever = bytes in flight per window.
//
// r11 proved the Ks-free math correct (swapped QK from global K, in-reg P,
// single barrier) but launch_bounds(256,8) forced 32 VGPRs and serialized the
// K loads inside the QK loop. This round fixes r11 instead of abandoning it:
//   1. Hoist ALL 20 K f32x4 loads to kernel entry, with V (8) and Q (4):
//      32 x f32x4 = 512 B/lane = 32 KB in flight PER WAVE, anchored by asm
//      data-pins. launch_bounds(256,3) (~168 VGPR cap) is the regime where
//      the compiler demonstrably keeps ~100+ regs live (r10: 104).
//   2. Pack K -> bf16 A-frags BEFORE the barrier (80 fp32 regs -> 40 bf16).
//      QK after the barrier is pure register MFMAs: no Ks LDS at all.
//   3. LDS = Vt only = 19456 B. ONE barrier. Softmax mask folded to unsigned
//      range checks (-40 VALU/wave).
// Tell: VGPR_Count ~140-160 => batching held. <100 => compiler chunked again
// (next escalation: inline-asm global_load_dwordx4).

#define B_ 4
#define L_ 2048
#define H_ 16
#define E_ 64
#define D_ 64
#define VT_STRIDE 152

typedef __attribute__((ext_vector_type(8))) short short8;
typedef __attribute__((ext_vector_type(4))) float f32x4;

__device__ __forceinline__ unsigned int f2bf(float x) {
  unsigned int b = __float_as_uint(x);
  b += 0x7fffu + ((b >> 16) & 1u);   // RNE to bf16
  return b >> 16;
}
__device__ __forceinline__ unsigned int pack2(float a, float b) {
  return f2bf(a) | (f2bf(b) << 16);
}
__device__ __forceinline__ short8 pack8(const f32x4& a, const f32x4& b) {
  union { short8 s; uint4 u; } r;
  r.u = make_uint4(pack2(a[0], a[1]), pack2(a[2], a[3]),
                   pack2(b[0], b[1]), pack2(b[2], b[3]));
  return r.s;
}
__device__ __forceinline__ int clampL(int k) {
  return k < 0 ? 0 : (k > (L_ - 1) ? (L_ - 1) : k);
}

__global__ __launch_bounds__(256, 3)
void local_attn_mfma(const float* __restrict__ qg,
                     const float* __restrict__ kg,
                     const float* __restrict__ vg,
                     float* __restrict__ og) {
  __shared__ __align__(16) unsigned short Vt[64 * VT_STRIDE];  // 19456 B, [dim][key_rel]

  const int t = threadIdx.x;
  const int q0 = blockIdx.x * 64;
  const int h = blockIdx.y;
  const int b = blockIdx.z;
  const int kstart = q0 - 32;
  const int wave = t >> 6;
  const int lane = t & 63;
  const int col16 = lane & 15;
  const int quad = lane >> 4;

  // ---- Issue ALL loads at entry: K (20), V (8), Q (4) f32x4 = 512 B/lane ----
  f32x4 kf[20];
  #pragma unroll
  for (int tt = 0; tt < 5; ++tt) {
    const int key = clampL(kstart + wave * 16 + tt * 16 + col16);
    const float* pk = kg + ((size_t)(b * L_ + key) * H_ + h) * E_ + quad * 8;
    kf[tt * 4 + 0] = *(const f32x4*)pk;
    kf[tt * 4 + 1] = *(const f32x4*)(pk + 4);
    kf[tt * 4 + 2] = *(const f32x4*)(pk + 32);
    kf[tt * 4 + 3] = *(const f32x4*)(pk + 36);
  }
  const int kp = t >> 2;               // key pair -> keys kstart+2kp, +2kp+1
  const int dq = t & 3;                // dim quarter: dims dq*16 .. +15
  f32x4 va[4], vc[4];
  {
    const int k0 = clampL(kstart + 2 * kp);
    const int k1 = clampL(kstart + 2 * kp + 1);
    const float* p0 = vg + ((size_t)(b * L_ + k0) * H_ + h) * D_ + dq * 16;
    const float* p1 = vg + ((size_t)(b * L_ + k1) * H_ + h) * D_ + dq * 16;
    #pragma unroll
    for (int i = 0; i < 4; ++i) va[i] = *(const f32x4*)(p0 + i * 4);
    #pragma unroll
    for (int i = 0; i < 4; ++i) vc[i] = *(const f32x4*)(p1 + i * 4);
  }
  f32x4 qf0, qf1, qf2, qf3;
  {
    const float* pq = qg + ((size_t)(b * L_ + q0 + wave * 16 + col16) * H_ + h) * E_ + quad * 8;
    qf0 = *(const f32x4*)pq;
    qf1 = *(const f32x4*)(pq + 4);
    qf2 = *(const f32x4*)(pq + 32);
    qf3 = *(const f32x4*)(pq + 36);
  }

  // ---- Data-pin anchors: loads cannot sink below uses of their results ----
  asm volatile("" ::
      "v"(kf[0]),  "v"(kf[1]),  "v"(kf[2]),  "v"(kf[3]),  "v"(kf[4]),
      "v"(kf[5]),  "v"(kf[6]),  "v"(kf[7]),  "v"(kf[8]),  "v"(kf[9]),
      "v"(kf[10]), "v"(kf[11]), "v"(kf[12]), "v"(kf[13]), "v"(kf[14]),
      "v"(kf[15]), "v"(kf[16]), "v"(kf[17]), "v"(kf[18]), "v"(kf[19]));
  asm volatile("" ::
      "v"(va[0]), "v"(va[1]), "v"(va[2]), "v"(va[3]),
      "v"(vc[0]), "v"(vc[1]), "v"(vc[2]), "v"(vc[3]),
      "v"(qf0), "v"(qf1), "v"(qf2), "v"(qf3));
  __builtin_amdgcn_sched_barrier(0);

  // ---- Pack V -> Vt (bf16 transposed), zero-pad key cols 128..143 ----
  #pragma unroll
  for (int i = 0; i < 4; ++i)
    #pragma unroll
    for (int j = 0; j < 4; ++j) {
      int d = dq * 16 + i * 4 + j;
      *(unsigned int*)&Vt[d * VT_STRIDE + 2 * kp] = pack2(va[i][j], vc[i][j]);
    }
  *(uint2*)&Vt[(t >> 2) * VT_STRIDE + 128 + (t & 3) * 4] = make_uint2(0u, 0u);

  // ---- Pack Q and K fragments (frees the 80 fp32 K regs -> 40 bf16) ----
  const short8 qa0 = pack8(qf0, qf1);
  const short8 qa1 = pack8(qf2, qf3);
  short8 kb0[5], kb1[5];
  #pragma unroll
  for (int tt = 0; tt < 5; ++tt) {
    kb0[tt] = pack8(kf[tt * 4 + 0], kf[tt * 4 + 1]);
    kb1[tt] = pack8(kf[tt * 4 + 2], kf[tt * 4 + 3]);
  }

  __syncthreads();   // the ONLY barrier (Vt visibility)

  // ---- QK swapped, pure-register MFMAs: acc = S^T tile.
  //      Lane holds S[key = wave*16 + tt*16 + quad*4 + r][query = col16]. ----
  f32x4 acc[5];
  #pragma unroll
  for (int tt = 0; tt < 5; ++tt) {
    f32x4 c = {0.f, 0.f, 0.f, 0.f};
    c = __builtin_amdgcn_mfma_f32_16x16x32_bf16(kb0[tt], qa0, c, 0, 0, 0);
    c = __builtin_amdgcn_mfma_f32_16x16x32_bf16(kb1[tt], qa1, c, 0, 0, 0);
    acc[tt] = c;
  }

  // ---- Mask + softmax. Query = col16 (fixed per lane); keys over (tt,quad,r).
  //      Cross-lane reduce = quads only: shfl_xor 16, 32. ----
  float mx = -1e30f;
  #pragma unroll
  for (int tt = 0; tt < 5; ++tt)
    #pragma unroll
    for (int r = 0; r < 4; ++r) {
      const int k_loc = tt * 16 + quad * 4 + r;          // key rel to wave band
      const int gkey = kstart + wave * 16 + k_loc;       // global key
      const bool ok = ((unsigned)(k_loc - col16) < 64u) &&
                      ((unsigned)gkey < (unsigned)L_);
      const float v = ok ? acc[tt][r] * 0.125f : -1e30f; // scale = 1/sqrt(64)
      acc[tt][r] = v;
      mx = fmaxf(mx, v);
    }
  mx = fmaxf(mx, __shfl_xor(mx, 16));
  mx = fmaxf(mx, __shfl_xor(mx, 32));
  float s = 0.f;
  #pragma unroll
  for (int tt = 0; tt < 5; ++tt)
    #pragma unroll
    for (int r = 0; r < 4; ++r) {
      const float e = __expf(acc[tt][r] - mx);
      acc[tt][r] = e;
      s += e;
    }
  s += __shfl_xor(s, 16);
  s += __shfl_xor(s, 32);
  const float inv = 1.0f / s;          // >= 32 valid keys -> s >= 1

  // ---- P -> PV A-frags IN REGISTER (lane-local by construction).
  //      elem j of pa[ks] = P[col16][32ks+16(j>>2)+4quad+(j&3)]
  //      = acc[2ks + (j>>2)][j&3]. Tail frag: elems 4..7 = 0. ----
  short8 pa[3];
  {
    union { short8 s8; uint4 u4; } w;
    w.u4 = make_uint4(pack2(acc[0][0] * inv, acc[0][1] * inv),
                      pack2(acc[0][2] * inv, acc[0][3] * inv),
                      pack2(acc[1][0] * inv, acc[1][1] * inv),
                      pack2(acc[1][2] * inv, acc[1][3] * inv));
    pa[0] = w.s8;
    w.u4 = make_uint4(pack2(acc[2][0] * inv, acc[2][1] * inv),
                      pack2(acc[2][2] * inv, acc[2][3] * inv),
                      pack2(acc[3][0] * inv, acc[3][1] * inv),
                      pack2(acc[3][2] * inv, acc[3][3] * inv));
    pa[1] = w.s8;
    w.u4 = make_uint4(pack2(acc[4][0] * inv, acc[4][1] * inv),
                      pack2(acc[4][2] * inv, acc[4][3] * inv), 0u, 0u);
    pa[2] = w.s8;
  }

  // ---- PV: per dim-tile nt, 3 K=32 steps. B elem j = V[key(quad*8+j)][dim]:
  //      two uint2 (4 consecutive keys each) at cols base+quad*4 and +16. ----
  f32x4 oacc[4];
  #pragma unroll
  for (int nt = 0; nt < 4; ++nt) oacc[nt] = (f32x4){0.f, 0.f, 0.f, 0.f};
  #pragma unroll
  for (int nt = 0; nt < 4; ++nt) {
    const int rowb = (nt * 16 + col16) * VT_STRIDE;
    #pragma unroll
    for (int ks = 0; ks < 3; ++ks) {
      union { short8 s8; uint2 u2[2]; } vb;
      vb.u2[0] = *(const uint2*)&Vt[rowb + wave * 16 + ks * 32 + quad * 4];
      vb.u2[1] = *(const uint2*)&Vt[rowb + wave * 16 + ks * 32 + 16 + quad * 4];
      oacc[nt] = __builtin_amdgcn_mfma_f32_16x16x32_bf16(pa[ks], vb.s8, oacc[nt], 0, 0, 0);
    }
  }

  // ---- Store O (fp32). C: row = quad*4+r (query), col = col16 (dim) ----
  #pragma unroll
  for (int r = 0; r < 4; ++r) {
    const int q = q0 + wave * 16 + quad * 4 + r;
    float* orow = og + ((size_t)(b * L_ + q) * H_ + h) * D_;
    #pragma unroll
    for (int nt = 0; nt < 4; ++nt)
      orow[nt * 16 + col16] = oacc[nt][r];
  }
}

extern "C" void kernel_launch(void* const* d_in, const int* in_sizes, int n_in,
                              void* d_out, int out_size, void* d_ws, size_t ws_size,
                              hipStream_t stream) {
  const float* q = (const float*)d_in[0];
  const float* k = (const float*)d_in[1];
  const float* v = (const float*)d_in[2];
  float* o = (float*)d_out;
  dim3 grid(L_ / 64, H_, B_);
  local_attn_mfma<<<grid, dim3(256), 0, stream>>>(q, k, v, o);
}